// Round 2
// baseline (797.392 us; speedup 1.0000x reference)
//
#include <hip/hip_runtime.h>
#include <hip/hip_bf16.h>

// Problem constants
#define S_LEN 8192
#define NH    16
#define HD    128      // head dim
#define HID   2048     // hidden
#define CHUNK 12
#define MP    12
#define CTX   24
#define POS   13
#define NBLK  683      // ceil(8192/12)

typedef short bf16x8 __attribute__((ext_vector_type(8)));
typedef float f32x4  __attribute__((ext_vector_type(4)));
typedef unsigned short u16;
typedef u16 u16x8 __attribute__((ext_vector_type(8)));
typedef u16 u16x4 __attribute__((ext_vector_type(4)));

#define MFMA16 __builtin_amdgcn_mfma_f32_16x16x32_bf16

__device__ __forceinline__ void glds16(const u16* g, u16* l) {
  __builtin_amdgcn_global_load_lds(
      (__attribute__((address_space(1))) void*)(void*)g,
      (__attribute__((address_space(3))) void*)l, 16, 0, 0);
}

__device__ __forceinline__ u16 f2b(float f) {
  __hip_bfloat16 h = __float2bfloat16(f);
  return *(u16*)&h;
}
__device__ __forceinline__ float b2f(u16 u) {
  __hip_bfloat16 h = *(__hip_bfloat16*)&u;
  return __bfloat162float(h);
}

// ---------------------------------------------------------------- convert
// f32 -> bf16, n divisible by 4. grid: n/4/256 blocks x 256.
__global__ __launch_bounds__(256) void f32_to_bf16(const float* __restrict__ in,
                                                   u16* __restrict__ out, int n) {
  int i = (blockIdx.x * 256 + threadIdx.x) * 4;
  if (i < n) {
    float4 v = *(const float4*)(in + i);
    u16x4 o = {f2b(v.x), f2b(v.y), f2b(v.z), f2b(v.w)};
    *(u16x4*)(out + i) = o;
  }
}

// ---------------------------------------------------------------- transpose
// W f32 [K=2048][N=2048] -> Wt bf16 [N][K]. Grid (32,32), block 256.
__global__ __launch_bounds__(256) void transpose2048(const float* __restrict__ in,
                                                     u16* __restrict__ out) {
  __shared__ u16 t[64][72]; // +8 pad breaks bank conflicts
  const int bx = blockIdx.x * 64, by = blockIdx.y * 64;
  const int x = threadIdx.x & 63;
  const int y4 = threadIdx.x >> 6;
  for (int r = y4; r < 64; r += 4)
    t[r][x] = f2b(in[(size_t)(by + r) * HID + bx + x]);
  __syncthreads();
  for (int r = y4; r < 64; r += 4)
    out[(size_t)(bx + r) * HID + by + x] = t[x][r];
}

// ---------------------------------------------------------------- q scale
// qs[d] = D^-0.5 / softplus(0) * softplus(pds[d]);  1 block x 128
__global__ void qscale_kernel(const float* __restrict__ pds, float* __restrict__ qs) {
  int d = threadIdx.x;
  float x = pds[d];
  float sp = log1pf(expf(x));
  qs[d] = 0.08838834764831845f * 1.4426950408889634f * sp;
}

// ---------------------------------------------------------------- rel_k
// rel[p][h*128+d] = sum_c pos[p][c] * Wrel[c][h*128+d];  grid(13,16) block 128
__global__ void relk_kernel(const float* __restrict__ pos, const float* __restrict__ Wrel,
                            u16* __restrict__ rel) {
  const int p = blockIdx.x, h = blockIdx.y, d = threadIdx.x;
  float acc = 0.f;
  const float* wp = Wrel + h * HD + d;
  const float* pp = pos + (size_t)p * HID;
  for (int c = 0; c < HID; ++c)
    acc += pp[c] * wp[(size_t)c * HID];
  rel[(size_t)p * HID + h * HD + d] = f2b(acc);
}

// ---------------------------------------------------------------- GEMM
// C[M=8192][N=2048] = A[M][K=2048] * Bt[N][K]^T, bf16 in, f32 accum.
// m97 structure: 128x128 tile, BK=32, 4 waves of 64x64, glds width-16 staging.
// colscale (optional): C[row][col] *= colscale[col & 127]
// Cf != null -> store f32 to Cf; else store bf16 to Co.
__global__ __launch_bounds__(256) void gemm_bt(const u16* __restrict__ A,
                                               const u16* __restrict__ Bt,
                                               u16* __restrict__ Co,
                                               float* __restrict__ Cf,
                                               const float* __restrict__ colscale) {
  __shared__ u16 lA[128 * 32]; // [m][k] row-major, 64B rows (no pad: glds layout)
  __shared__ u16 lB[128 * 32]; // [n][k]
  const int tid = threadIdx.x;
  const int lane = tid & 63, w = tid >> 6;
  const int quad = lane >> 4, l = lane & 15;
  const int bm = blockIdx.x * 128, bn = blockIdx.y * 128;
  const int wm = (w >> 1) * 64, wn = (w & 1) * 64;

  f32x4 acc[4][4] = {};

  for (int kt = 0; kt < HID; kt += 32) {
#pragma unroll
    for (int r = 0; r < 2; ++r) {
      int o = w * 1024 + r * 4096 + lane * 16; // byte offset within 8KB tile
      int m = o >> 6;                          // row (64B per row)
      int ke = (o & 63) >> 1;                  // k element within row
      glds16(A + (size_t)(bm + m) * HID + kt + ke, lA + w * 512 + r * 2048);
      glds16(Bt + (size_t)(bn + m) * HID + kt + ke, lB + w * 512 + r * 2048);
    }
    __syncthreads(); // drains vmcnt (glds) per compiler barrier semantics

    bf16x8 af[4], bfr[4];
#pragma unroll
    for (int i = 0; i < 4; ++i)
      af[i] = *(const bf16x8*)(lA + (wm + i * 16 + l) * 32 + quad * 8);
#pragma unroll
    for (int j = 0; j < 4; ++j)
      bfr[j] = *(const bf16x8*)(lB + (wn + j * 16 + l) * 32 + quad * 8);
#pragma unroll
    for (int i = 0; i < 4; ++i)
#pragma unroll
      for (int j = 0; j < 4; ++j)
        acc[i][j] = MFMA16(af[i], bfr[j], acc[i][j], 0, 0, 0);
    __syncthreads();
  }

#pragma unroll
  for (int i = 0; i < 4; ++i)
#pragma unroll
    for (int j = 0; j < 4; ++j)
#pragma unroll
      for (int r = 0; r < 4; ++r) {
        int row = bm + wm + i * 16 + quad * 4 + r;
        int col = bn + wn + j * 16 + l;
        float v = acc[i][j][r];
        if (colscale) v *= colscale[col & (HD - 1)];
        if (Cf) Cf[(size_t)row * HID + col] = v;
        else    Co[(size_t)row * HID + col] = f2b(v);
      }
}

// ---------------------------------------------------------------- attention
// 1 wave per (n,h). Scores via MFMA (Q/K in LDS), rel B-frag direct from
// global, softcap+softmax in regs with intra-quad shuffles, P through LDS,
// PV via MFMA with V transposed in LDS.
__global__ __launch_bounds__(64) void attn_kernel(const u16* __restrict__ qg,
                                                  const u16* __restrict__ kg,
                                                  const u16* __restrict__ vg,
                                                  const u16* __restrict__ relg,
                                                  u16* __restrict__ og) {
  __shared__ u16 qs[16][136]; // pad 128->136: breaks 16-way bank conflict
  __shared__ u16 ks[32][136];
  __shared__ u16 vt[128][40]; // [d][ctx], ctx padded 32->40
  __shared__ u16 ps[16][40];  // P in A-layout [c][ctx]
  const int n = blockIdx.x, h = blockIdx.y;
  const int lane = threadIdx.x;
  const int quad = lane >> 4, l = lane & 15;
  const int base = n * CHUNK;
  const u16x8 zero8 = {0, 0, 0, 0, 0, 0, 0, 0};

  // stage Q rows (c 0..15; pad rows zero)
#pragma unroll
  for (int i = 0; i < 4; ++i) {
    int id = lane + 64 * i;
    int c = id >> 4, dc = id & 15;
    int s = base + c;
    u16x8 v = (c < CHUNK && s < S_LEN)
                  ? *(const u16x8*)(qg + (size_t)s * HID + h * HD + dc * 8)
                  : zero8;
    *(u16x8*)&qs[c][dc * 8] = v;
  }
  // stage K context rows (ctx 0..31; OOB -> zero)
#pragma unroll
  for (int i = 0; i < 8; ++i) {
    int id = lane + 64 * i;
    int ctx = id >> 4, dc = id & 15;
    int s = base + ctx - MP;
    u16x8 v = (ctx < CTX && s >= 0 && s < S_LEN)
                  ? *(const u16x8*)(kg + (size_t)s * HID + h * HD + dc * 8)
                  : zero8;
    *(u16x8*)&ks[ctx][dc * 8] = v;
  }
  // stage V transposed: vt[d][ctx]
#pragma unroll
  for (int i = 0; i < 8; ++i) {
    int id = lane + 64 * i;
    int ctx = id & 31, dc = id >> 5;
    int s = base + ctx - MP;
    u16x8 v = (ctx < CTX && s >= 0 && s < S_LEN)
                  ? *(const u16x8*)(vg + (size_t)s * HID + h * HD + dc * 8)
                  : zero8;
#pragma unroll
    for (int jj = 0; jj < 8; ++jj) vt[dc * 8 + jj][ctx] = v[jj];
  }
  __syncthreads();

  // scores: ac0 (ctx 0..15), ac1 (ctx 16..31), bd (pos 0..15)
  f32x4 ac0 = {0, 0, 0, 0}, ac1 = {0, 0, 0, 0}, bd = {0, 0, 0, 0};
#pragma unroll
  for (int t = 0; t < 4; ++t) {
    int d0 = t * 32;
    bf16x8 aQ = *(const bf16x8*)&qs[l][d0 + quad * 8];
    bf16x8 bK0 = *(const bf16x8*)&ks[l][d0 + quad * 8];
    bf16x8 bK1 = *(const bf16x8*)&ks[16 + l][d0 + quad * 8];
    bf16x8 bR = {0, 0, 0, 0, 0, 0, 0, 0};
    if (l < POS)
      bR = *(const bf16x8*)(relg + (size_t)l * HID + h * HD + d0 + quad * 8);
    ac0 = MFMA16(aQ, bK0, ac0, 0, 0, 0);
    ac1 = MFMA16(aQ, bK1, ac1, 0, 0, 0);
    bd = MFMA16(aQ, bR, bd, 0, 0, 0);
  }

  // softcap + softmax (C/D layout: row c = quad*4+r, col ctx = l / 16+l)
  float p0[4], p1[4];
#pragma unroll
  for (int r = 0; r < 4; ++r) {
    int c = quad * 4 + r;
    int pi0 = l - c;        // rel pos for ctx0 = l
    int pi1 = 16 + l - c;   // rel pos for ctx1 = 16+l
    int sp0 = pi0 < 0 ? 0 : (pi0 > 15 ? 15 : pi0);
    int sp1 = pi1 < 0 ? 0 : (pi1 > 15 ? 15 : pi1);
    float b0 = __shfl(bd[r], quad * 16 + sp0, 64);
    float b1 = __shfl(bd[r], quad * 16 + sp1, 64);
    b0 = (pi0 >= 0 && pi0 < POS) ? b0 : 0.0f;
    b1 = (pi1 >= 0 && pi1 < POS) ? b1 : 0.0f;
    float s0 = tanhf((ac0[r] + b0) * (1.0f / 50.0f)) * 50.0f;
    float s1 = tanhf((ac1[r] + b1) * (1.0f / 50.0f)) * 50.0f;
    bool v1 = (l < (CTX - 16)); // ctx1 < 24
    if (!v1) s1 = -1e30f;
    float mx = fmaxf(s0, s1);
#pragma unroll
    for (int d = 1; d < 16; d <<= 1) mx = fmaxf(mx, __shfl_xor(mx, d, 64));
    float e0 = __expf(s0 - mx);
    float e1 = v1 ? __expf(s1 - mx) : 0.0f;
    float sm = e0 + e1;
#pragma unroll
    for (int d = 1; d < 16; d <<= 1) sm += __shfl_xor(sm, d, 64);
    float inv = 1.0f / sm;
    p0[r] = e0 * inv;
    p1[r] = e1 * inv;
  }
#pragma unroll
  for (int r = 0; r < 4; ++r) {
    int c = quad * 4 + r;
    ps[c][l] = f2b(p0[r]);
    ps[c][16 + l] = f2b(p1[r]); // covers ctx 16..31 (zeros where invalid)
  }
  __syncthreads();

  // PV: out[c][d] = sum_ctx P[c][ctx] * V[ctx][d], K=32 in one MFMA
  bf16x8 aP = *(const bf16x8*)&ps[l][quad * 8];
#pragma unroll
  for (int nt = 0; nt < 8; ++nt) {
    bf16x8 bV = *(const bf16x8*)&vt[nt * 16 + l][quad * 8];
    f32x4 o = {0, 0, 0, 0};
    o = MFMA16(aP, bV, o, 0, 0, 0);
#pragma unroll
    for (int r = 0; r < 4; ++r) {
      int c = quad * 4 + r;
      int s = base + c;
      if (c < CHUNK && s < S_LEN)
        og[(size_t)s * HID + h * HD + nt * 16 + l] = f2b(o[r]);
    }
  }
}

// ---------------------------------------------------------------- launch
extern "C" void kernel_launch(void* const* d_in, const int* in_sizes, int n_in,
                              void* d_out, int out_size, void* d_ws, size_t ws_size,
                              hipStream_t stream) {
  const float* x = (const float*)d_in[0];
  const float* pos = (const float*)d_in[1];
  const float* Wq = (const float*)d_in[2];
  const float* Wk = (const float*)d_in[3];
  const float* Wv = (const float*)d_in[4];
  const float* Wrel = (const float*)d_in[5];
  const float* Wpost = (const float*)d_in[6];
  const float* pds = (const float*)d_in[7];

  char* ws = (char*)d_ws;
  const size_t SZ_W = (size_t)HID * HID * 2;   // 8 MB  (bf16 2048x2048)
  const size_t SZ_X = (size_t)S_LEN * HID * 2; // 32 MB (bf16 8192x2048)
  u16* wtq = (u16*)(ws + 0 * SZ_W);
  u16* wtk = (u16*)(ws + 1 * SZ_W);
  u16* wtv = (u16*)(ws + 2 * SZ_W);
  u16* wtp = (u16*)(ws + 3 * SZ_W);
  u16* xb  = (u16*)(ws + 4 * SZ_W + 0 * SZ_X);
  u16* Qb  = (u16*)(ws + 4 * SZ_W + 1 * SZ_X);
  u16* Kb  = (u16*)(ws + 4 * SZ_W + 2 * SZ_X);
  u16* Vb  = (u16*)(ws + 4 * SZ_W + 3 * SZ_X);
  u16* AO  = xb; // alias: xb is dead after the V GEMM
  u16* REL = (u16*)(ws + 4 * SZ_W + 4 * SZ_X);
  float* QS = (float*)(ws + 4 * SZ_W + 4 * SZ_X + 65536);

  const int NX = S_LEN * HID; // 16.7M
  f32_to_bf16<<<NX / 4 / 256, 256, 0, stream>>>(x, xb, NX);

  dim3 tg(32, 32);
  transpose2048<<<tg, 256, 0, stream>>>(Wq, wtq);
  transpose2048<<<tg, 256, 0, stream>>>(Wk, wtk);
  transpose2048<<<tg, 256, 0, stream>>>(Wv, wtv);
  transpose2048<<<tg, 256, 0, stream>>>(Wpost, wtp);
  qscale_kernel<<<1, 128, 0, stream>>>(pds, QS);
  relk_kernel<<<dim3(POS, NH), 128, 0, stream>>>(pos, Wrel, REL);

  dim3 gg(S_LEN / 128, HID / 128); // 64 x 16
  gemm_bt<<<gg, 256, 0, stream>>>(xb, wtq, Qb, nullptr, QS);
  gemm_bt<<<gg, 256, 0, stream>>>(xb, wtk, Kb, nullptr, nullptr);
  gemm_bt<<<gg, 256, 0, stream>>>(xb, wtv, Vb, nullptr, nullptr);

  attn_kernel<<<dim3(NBLK, NH), 64, 0, stream>>>(Qb, Kb, Vb, REL, AO);

  gemm_bt<<<gg, 256, 0, stream>>>(AO, wtp, nullptr, (float*)d_out, nullptr);
}

// Round 3
// 636.172 us; speedup vs baseline: 1.2534x; 1.2534x over previous
//
#include <hip/hip_runtime.h>
#include <hip/hip_bf16.h>

// Problem constants
#define S_LEN 8192
#define NH    16
#define HD    128      // head dim
#define HID   2048     // hidden
#define NQKV  6144     // fused QKV output width
#define CHUNK 12
#define MP    12
#define CTX   24
#define POS   13
#define NBLK  683      // ceil(8192/12)

typedef short bf16x8 __attribute__((ext_vector_type(8)));
typedef float f32x4  __attribute__((ext_vector_type(4)));
typedef unsigned short u16;
typedef u16 u16x8 __attribute__((ext_vector_type(8)));
typedef u16 u16x4 __attribute__((ext_vector_type(4)));

#define MFMA16 __builtin_amdgcn_mfma_f32_16x16x32_bf16

__device__ __forceinline__ void glds16(const u16* g, u16* l) {
  __builtin_amdgcn_global_load_lds(
      (__attribute__((address_space(1))) void*)(void*)g,
      (__attribute__((address_space(3))) void*)l, 16, 0, 0);
}

__device__ __forceinline__ u16 f2b(float f) {
  __hip_bfloat16 h = __float2bfloat16(f);
  return *(u16*)&h;
}

// ---------------------------------------------------------------- convert
__global__ __launch_bounds__(256) void f32_to_bf16(const float* __restrict__ in,
                                                   u16* __restrict__ out, int n) {
  int i = (blockIdx.x * 256 + threadIdx.x) * 4;
  if (i < n) {
    float4 v = *(const float4*)(in + i);
    u16x4 o = {f2b(v.x), f2b(v.y), f2b(v.z), f2b(v.w)};
    *(u16x4*)(out + i) = o;
  }
}

// ---------------------------------------------------------------- transpose x4
// z selects {Wq,Wk,Wv,Wpost}; out slab z: bf16 [N][K]. Grid (32,32,4), block 256.
__global__ __launch_bounds__(256) void transpose4(const float* __restrict__ W0,
                                                  const float* __restrict__ W1,
                                                  const float* __restrict__ W2,
                                                  const float* __restrict__ W3,
                                                  u16* __restrict__ out) {
  __shared__ u16 t[64][72];
  const int z = blockIdx.z;
  const float* in = (z == 0) ? W0 : (z == 1) ? W1 : (z == 2) ? W2 : W3;
  u16* dst = out + (size_t)z * HID * HID;
  const int bx = blockIdx.x * 64, by = blockIdx.y * 64;
  const int x = threadIdx.x & 63;
  const int y4 = threadIdx.x >> 6;
  for (int r = y4; r < 64; r += 4)
    t[r][x] = f2b(in[(size_t)(by + r) * HID + bx + x]);
  __syncthreads();
  for (int r = y4; r < 64; r += 4)
    dst[(size_t)(bx + r) * HID + by + x] = t[x][r];
}

// ---------------------------------------------------------------- q scale
__global__ void qscale_kernel(const float* __restrict__ pds, float* __restrict__ qs) {
  int d = threadIdx.x;
  float x = pds[d];
  float sp = log1pf(expf(x));
  qs[d] = 0.08838834764831845f * 1.4426950408889634f * sp;
}

// ---------------------------------------------------------------- rel_k
// split-K atomic: grid(8 colblk, 8 csplit), block 256. RELF must be zeroed.
__global__ __launch_bounds__(256) void relk_atomic(const float* __restrict__ pos,
                                                   const float* __restrict__ Wrel,
                                                   float* __restrict__ RELF) {
  const int col = blockIdx.x * 256 + threadIdx.x;
  const int c0 = blockIdx.y * 256;
  float acc[POS] = {};
  for (int c = c0; c < c0 + 256; ++c) {
    float wv = Wrel[(size_t)c * HID + col];
#pragma unroll
    for (int p = 0; p < POS; ++p) acc[p] += pos[p * HID + c] * wv;
  }
#pragma unroll
  for (int p = 0; p < POS; ++p) atomicAdd(&RELF[p * HID + col], acc[p]);
}

__global__ __launch_bounds__(256) void relk_cvt(const float* __restrict__ RELF,
                                                u16* __restrict__ REL) {
  int i = blockIdx.x * 256 + threadIdx.x;
  if (i < POS * HID) REL[i] = f2b(RELF[i]);
}

// ---------------------------------------------------------------- GEMM
// C[8192][NN] = A[8192][2048] * Bt[NN][2048]^T, bf16 in, f32 accum.
// BK=64 as two BK=32 sub-tiles (keeps 64B-row conflict-free LDS layout),
// one barrier pair per 64 K. colscale applies where col < csLimit.
__global__ __launch_bounds__(256) void gemm_bt(const u16* __restrict__ A,
                                               const u16* __restrict__ Bt,
                                               u16* __restrict__ Co,
                                               float* __restrict__ Cf,
                                               const float* __restrict__ colscale,
                                               int NN, int csLimit) {
  __shared__ u16 lA[2][128 * 32];
  __shared__ u16 lB[2][128 * 32];
  const int tid = threadIdx.x;
  const int lane = tid & 63, w = tid >> 6;
  const int quad = lane >> 4, l = lane & 15;
  const int bm = blockIdx.x * 128, bn = blockIdx.y * 128;
  const int wm = (w >> 1) * 64, wn = (w & 1) * 64;

  f32x4 acc[4][4] = {};

  for (int kt = 0; kt < HID; kt += 64) {
#pragma unroll
    for (int r = 0; r < 2; ++r) {
      int o = w * 1024 + r * 4096 + lane * 16; // byte offset within 8KB sub-tile
      int m = o >> 6;                          // row (64B per row)
      int ke = (o & 63) >> 1;                  // k element within row
      const u16* ga = A + (size_t)(bm + m) * HID + kt + ke;
      const u16* gb = Bt + (size_t)(bn + m) * HID + kt + ke;
      u16* dA = lA[0] + w * 512 + r * 2048;
      u16* dB = lB[0] + w * 512 + r * 2048;
      glds16(ga, dA);
      glds16(ga + 32, dA + 128 * 32);
      glds16(gb, dB);
      glds16(gb + 32, dB + 128 * 32);
    }
    __syncthreads();

#pragma unroll
    for (int kk = 0; kk < 2; ++kk) {
      bf16x8 af[4], bfr[4];
#pragma unroll
      for (int i = 0; i < 4; ++i)
        af[i] = *(const bf16x8*)(lA[kk] + (wm + i * 16 + l) * 32 + quad * 8);
#pragma unroll
      for (int j = 0; j < 4; ++j)
        bfr[j] = *(const bf16x8*)(lB[kk] + (wn + j * 16 + l) * 32 + quad * 8);
#pragma unroll
      for (int i = 0; i < 4; ++i)
#pragma unroll
        for (int j = 0; j < 4; ++j)
          acc[i][j] = MFMA16(af[i], bfr[j], acc[i][j], 0, 0, 0);
    }
    __syncthreads();
  }

#pragma unroll
  for (int i = 0; i < 4; ++i)
#pragma unroll
    for (int j = 0; j < 4; ++j)
#pragma unroll
      for (int r = 0; r < 4; ++r) {
        int row = bm + wm + i * 16 + quad * 4 + r;
        int col = bn + wn + j * 16 + l;
        float v = acc[i][j][r];
        if (colscale && col < csLimit) v *= colscale[col & (HD - 1)];
        if (Cf) Cf[(size_t)row * NN + col] = v;
        else    Co[(size_t)row * NN + col] = f2b(v);
      }
}

// ---------------------------------------------------------------- attention
// 1 wave per (n,h), QKV fused input (row stride 6144). Phase-union LDS:
// phase1 {qs,ks} overlaid by phase2 {vt,ps}; V prefetched to regs at start.
__global__ __launch_bounds__(64) void attn_kernel(const u16* __restrict__ qkv,
                                                  const u16* __restrict__ relg,
                                                  u16* __restrict__ og) {
  __shared__ char smem[13824];
  u16* qs = (u16*)smem;            // [16][136] phase1 (4352 B)
  u16* ks = (u16*)(smem + 4352);   // [32][136] phase1 (8704 B)
  u16* vt = (u16*)smem;            // [128][48] phase2 (12288 B)
  u16* ps = (u16*)(smem + 12288);  // [16][48]  phase2 (1536 B)
  const int n = blockIdx.x, h = blockIdx.y;
  const int lane = threadIdx.x;
  const int quad = lane >> 4, l = lane & 15;
  const int base = n * CHUNK;
  const u16x8 zero8 = {0, 0, 0, 0, 0, 0, 0, 0};

  const u16* qg = qkv + h * HD;
  const u16* kg = qkv + 2048 + h * HD;
  const u16* vg = qkv + 4096 + h * HD;

  // prefetch V into regs (written to LDS after scores)
  u16x8 vld[8];
#pragma unroll
  for (int i = 0; i < 8; ++i) {
    int id = lane + 64 * i;
    int ctx = id & 31, dc = id >> 5; // dc: 16 chunks of 8 d
    int s = base + ctx - MP;
    vld[i] = (ctx < CTX && s >= 0 && s < S_LEN)
                 ? *(const u16x8*)(vg + (size_t)s * NQKV + dc * 8)
                 : zero8;
  }

  // stage Q rows (c 0..15; pad rows zero)
#pragma unroll
  for (int i = 0; i < 4; ++i) {
    int id = lane + 64 * i;
    int c = id >> 4, dc = id & 15;
    int s = base + c;
    u16x8 v = (c < CHUNK && s < S_LEN)
                  ? *(const u16x8*)(qg + (size_t)s * NQKV + dc * 8)
                  : zero8;
    *(u16x8*)(qs + c * 136 + dc * 8) = v;
  }
  // stage K context rows (ctx 0..31; OOB -> zero)
#pragma unroll
  for (int i = 0; i < 8; ++i) {
    int id = lane + 64 * i;
    int ctx = id >> 4, dc = id & 15;
    int s = base + ctx - MP;
    u16x8 v = (ctx < CTX && s >= 0 && s < S_LEN)
                  ? *(const u16x8*)(kg + (size_t)s * NQKV + dc * 8)
                  : zero8;
    *(u16x8*)(ks + ctx * 136 + dc * 8) = v;
  }
  __syncthreads();

  // scores: ac0 (ctx 0..15), ac1 (ctx 16..31), bd (pos 0..15)
  f32x4 ac0 = {0, 0, 0, 0}, ac1 = {0, 0, 0, 0}, bd = {0, 0, 0, 0};
#pragma unroll
  for (int t = 0; t < 4; ++t) {
    int d0 = t * 32;
    bf16x8 aQ = *(const bf16x8*)(qs + l * 136 + d0 + quad * 8);
    bf16x8 bK0 = *(const bf16x8*)(ks + l * 136 + d0 + quad * 8);
    bf16x8 bK1 = *(const bf16x8*)(ks + (16 + l) * 136 + d0 + quad * 8);
    bf16x8 bR = {0, 0, 0, 0, 0, 0, 0, 0};
    if (l < POS)
      bR = *(const bf16x8*)(relg + (size_t)l * HID + h * HD + d0 + quad * 8);
    ac0 = MFMA16(aQ, bK0, ac0, 0, 0, 0);
    ac1 = MFMA16(aQ, bK1, ac1, 0, 0, 0);
    bd = MFMA16(aQ, bR, bd, 0, 0, 0);
  }

  // softcap + softmax (C/D layout: row c = quad*4+r, col ctx = l / 16+l)
  float p0[4], p1[4];
#pragma unroll
  for (int r = 0; r < 4; ++r) {
    int c = quad * 4 + r;
    int pi0 = l - c;
    int pi1 = 16 + l - c;
    int sp0 = pi0 < 0 ? 0 : (pi0 > 15 ? 15 : pi0);
    int sp1 = pi1 < 0 ? 0 : (pi1 > 15 ? 15 : pi1);
    float b0 = __shfl(bd[r], quad * 16 + sp0, 64);
    float b1 = __shfl(bd[r], quad * 16 + sp1, 64);
    b0 = (pi0 >= 0 && pi0 < POS) ? b0 : 0.0f;
    b1 = (pi1 >= 0 && pi1 < POS) ? b1 : 0.0f;
    float s0 = tanhf((ac0[r] + b0) * (1.0f / 50.0f)) * 50.0f;
    float s1 = tanhf((ac1[r] + b1) * (1.0f / 50.0f)) * 50.0f;
    bool v1 = (l < (CTX - 16));
    if (!v1) s1 = -1e30f;
    float mx = fmaxf(s0, s1);
#pragma unroll
    for (int d = 1; d < 16; d <<= 1) mx = fmaxf(mx, __shfl_xor(mx, d, 64));
    float e0 = __expf(s0 - mx);
    float e1 = v1 ? __expf(s1 - mx) : 0.0f;
    float sm = e0 + e1;
#pragma unroll
    for (int d = 1; d < 16; d <<= 1) sm += __shfl_xor(sm, d, 64);
    float inv = 1.0f / sm;
    p0[r] = e0 * inv;
    p1[r] = e1 * inv;
  }
  __syncthreads(); // all score-phase LDS reads drained before overlay writes

  // phase2: write vt (from prefetched regs) and ps into the union region
#pragma unroll
  for (int i = 0; i < 8; ++i) {
    int id = lane + 64 * i;
    int ctx = id & 31, dc = id >> 5;
#pragma unroll
    for (int jj = 0; jj < 8; ++jj) vt[(dc * 8 + jj) * 48 + ctx] = vld[i][jj];
  }
#pragma unroll
  for (int r = 0; r < 4; ++r) {
    int c = quad * 4 + r;
    ps[c * 48 + l] = f2b(p0[r]);
    ps[c * 48 + 16 + l] = f2b(p1[r]);
  }
  __syncthreads();

  // PV: out[c][d] = sum_ctx P[c][ctx] * V[ctx][d]
  bf16x8 aP = *(const bf16x8*)(ps + l * 48 + quad * 8);
#pragma unroll
  for (int nt = 0; nt < 8; ++nt) {
    bf16x8 bV = *(const bf16x8*)(vt + (nt * 16 + l) * 48 + quad * 8);
    f32x4 o = {0, 0, 0, 0};
    o = MFMA16(aP, bV, o, 0, 0, 0);
#pragma unroll
    for (int r = 0; r < 4; ++r) {
      int c = quad * 4 + r;
      int s = base + c;
      if (c < CHUNK && s < S_LEN)
        og[(size_t)s * HID + h * HD + nt * 16 + l] = f2b(o[r]);
    }
  }
}

// ---------------------------------------------------------------- launch
extern "C" void kernel_launch(void* const* d_in, const int* in_sizes, int n_in,
                              void* d_out, int out_size, void* d_ws, size_t ws_size,
                              hipStream_t stream) {
  const float* x = (const float*)d_in[0];
  const float* pos = (const float*)d_in[1];
  const float* Wq = (const float*)d_in[2];
  const float* Wk = (const float*)d_in[3];
  const float* Wv = (const float*)d_in[4];
  const float* Wrel = (const float*)d_in[5];
  const float* Wpost = (const float*)d_in[6];
  const float* pds = (const float*)d_in[7];

  char* ws = (char*)d_ws;
  u16* WT  = (u16*)(ws);                      // 4 x [2048][2048] bf16 = 32 MB
  u16* xb  = (u16*)(ws + 33554432);           // [8192][2048] bf16 = 32 MB
  u16* AO  = xb;                              // alias: xb dead after QKV GEMM
  u16* QKV = (u16*)(ws + 67108864);           // [8192][6144] bf16 = 96 MB
  float* RELF = (float*)(ws + 167772160);     // [13][2048] f32
  u16* REL = (u16*)(ws + 167878656);          // [13][2048] bf16
  float* QS = (float*)(ws + 167931904);       // [128] f32

  const int NX = S_LEN * HID;
  f32_to_bf16<<<NX / 4 / 256, 256, 0, stream>>>(x, xb, NX);

  transpose4<<<dim3(32, 32, 4), 256, 0, stream>>>(Wq, Wk, Wv, Wpost, WT);
  qscale_kernel<<<1, 128, 0, stream>>>(pds, QS);

  hipMemsetAsync(RELF, 0, POS * HID * sizeof(float), stream);
  relk_atomic<<<dim3(8, 8), 256, 0, stream>>>(pos, Wrel, RELF);
  relk_cvt<<<(POS * HID + 255) / 256, 256, 0, stream>>>(RELF, REL);

  // fused QKV GEMM: Bt rows 0..6143 of WT; colscale on Q columns only
  gemm_bt<<<dim3(64, 48), 256, 0, stream>>>(xb, WT, QKV, nullptr, QS, NQKV, 2048);

  attn_kernel<<<dim3(NBLK, NH), 64, 0, stream>>>(QKV, REL, AO);

  // post GEMM: Bt = transposed Wpost (slab 3), f32 out
  gemm_bt<<<dim3(64, 16), 256, 0, stream>>>(AO, WT + (size_t)3 * HID * HID,
                                            nullptr, (float*)d_out, nullptr, HID, 0);
}